// Round 3
// baseline (861.593 us; speedup 1.0000x reference)
//
#include <hip/hip_runtime.h>
#include <hip/hip_bf16.h>

#define N_NODES 100000
#define N_TYPE  50000
#define SCAN_E  1024
#define NBUCK   98          // ceil(100000/1024)
#define NXCD    8
#define SEGCAP  3072        // per-(bucket,xcd) capacity; mean ~2041, sd ~45

typedef short bf16x8 __attribute__((ext_vector_type(8)));
typedef float f32x4  __attribute__((ext_vector_type(4)));
typedef unsigned short u16x4 __attribute__((ext_vector_type(4)));

__device__ inline unsigned short f2bf(float f) {
  union { float f; unsigned u; } x; x.f = f;
  unsigned r = (x.u + 0x7fff + ((x.u >> 16) & 1)) >> 16;  // RNE
  return (unsigned short)r;
}

// ---------------- prep: bf16 transposed weights + combined bias ------------------------------
// M0T[n][k] (128x128), M1T[n][k] (128x256), W2T[n][k] (64x128), cb[256] fp32
__global__ __launch_bounds__(256) void prep_small_kernel(
    const float* __restrict__ fc0_w, const float* __restrict__ fc1_w,
    const float* __restrict__ fc0_b, const float* __restrict__ fc1_b,
    const float* __restrict__ W1, const float* __restrict__ W2,
    unsigned short* __restrict__ M0T, unsigned short* __restrict__ M1T,
    unsigned short* __restrict__ W2T, float* __restrict__ cb) {
  int idx = blockIdx.x * 256 + threadIdx.x;
  if (idx < 16384) {                       // M0T: i=k (0..127), j=n (0..127)
    int i = idx >> 7, j = idx & 127;
    float s = 0.f;
    #pragma unroll 4
    for (int o = 0; o < 128; ++o) s = fmaf(fc0_w[o * 128 + i], W1[o * 128 + j], s);
    M0T[j * 128 + i] = f2bf(s);
  } else if (idx < 49152) {                // M1T: i=k (0..255), j=n (0..127)
    int r = idx - 16384;
    int i = r >> 7, j = r & 127;
    float s = 0.f;
    #pragma unroll 4
    for (int o = 0; o < 128; ++o) s = fmaf(fc1_w[o * 256 + i], W1[o * 128 + j], s);
    M1T[j * 256 + i] = f2bf(s);
  } else if (idx < 57344) {                // W2T: k (0..127), n (0..63)
    int r = idx - 49152;
    int k = r >> 6, n = r & 63;
    W2T[n * 128 + k] = f2bf(W2[k * 64 + n]);
  } else if (idx < 57600) {                // cb
    int r = idx - 57344;
    int t = r >> 7, j = r & 127;
    const float* bb = t ? fc1_b : fc0_b;
    float s = 0.f;
    for (int o = 0; o < 128; ++o) s = fmaf(bb[o], W1[o * 128 + j], s);
    cb[r] = s;
  }
}

// ---------------- bf16 MFMA GEMM: C[M][NC] = act(A[M][KTOT]) @ BT^T (+bc) --------------------
// A fp32 row-major [M][KTOT]; BT bf16 [NC][KTOT] (n-major). act: relu(a+bk[k]) if RELU_BIAS.
// 256 thr = 4 waves in 2x2 grid; tile 64 rows x NC cols; K chunked by 128.
template <int NC, int KTOT, bool RELU_BIAS>
__global__ __launch_bounds__(256) void mfma_gemm_kernel(
    const float* __restrict__ A, const unsigned short* __restrict__ BT,
    const float* __restrict__ bk, const float* __restrict__ bc,
    float* __restrict__ C, int M) {
  constexpr int NREP = NC / 32;            // per-wave 16-col frags (wave covers NC/2 cols)
  __shared__ unsigned short As[64 * 128];  // 16 KiB, swizzled
  __shared__ unsigned short Bs[NC * 128];  // NC*256 B, swizzled

  const int tid = threadIdx.x;
  const int row0 = blockIdx.x * 64;
  const int wave = tid >> 6, lane = tid & 63;
  const int wr = wave >> 1, wc = wave & 1;
  const int lm = lane & 15;
  const int lk16 = (lane >> 4) * 16;       // byte offset of k-block within 64B k-step

  f32x4 acc[2][NREP];
  #pragma unroll
  for (int i = 0; i < 2; ++i)
    #pragma unroll
    for (int j = 0; j < NREP; ++j) acc[i][j] = (f32x4){0.f, 0.f, 0.f, 0.f};

  for (int kc = 0; kc < KTOT; kc += 128) {
    if (kc) __syncthreads();
    // ---- stage A: fp32 -> bf16, swizzled rows ----
    {
      const int r = tid >> 2;              // 0..63
      const int cg = tid & 3;
      int gr = row0 + r; if (gr > M - 1) gr = M - 1;
      const float* arow = A + (size_t)gr * KTOT + kc;
      char* asrow = (char*)As + r * 256;
      const int swz = (r & 7) << 4;
      #pragma unroll
      for (int i = 0; i < 8; ++i) {
        const int c = i * 4 + cg;          // float4 chunk; k0 = c*4
        float4 v = *(const float4*)(arow + c * 4);
        if (RELU_BIAS) {
          const float4 b = *(const float4*)(bk + kc + c * 4);
          v.x = fmaxf(v.x + b.x, 0.f);
          v.y = fmaxf(v.y + b.y, 0.f);
          v.z = fmaxf(v.z + b.z, 0.f);
          v.w = fmaxf(v.w + b.w, 0.f);
        }
        u16x4 q = {f2bf(v.x), f2bf(v.y), f2bf(v.z), f2bf(v.w)};
        *(u16x4*)(asrow + ((c * 8) ^ swz)) = q;
      }
    }
    // ---- stage B: bf16 copy, swizzled rows ----
    {
      constexpr int CHUNKS = NC * 16;      // 16B chunks
      #pragma unroll
      for (int i = 0; i < CHUNKS / 256; ++i) {
        const int id = i * 256 + tid;
        const int n = id >> 4, k16 = id & 15;
        const uint4 w = *(const uint4*)((const char*)BT + ((size_t)n * KTOT + kc) * 2 + k16 * 16);
        *(uint4*)((char*)Bs + ((n * 256 + k16 * 16) ^ ((n & 7) << 4))) = w;
      }
    }
    __syncthreads();
    // ---- MFMA ----
    #pragma unroll
    for (int ks = 0; ks < 4; ++ks) {
      bf16x8 a[2];
      #pragma unroll
      for (int m = 0; m < 2; ++m) {
        const int r = wr * 32 + m * 16 + lm;
        a[m] = *(bf16x8*)((char*)As + ((r * 256 + ks * 64 + lk16) ^ ((r & 7) << 4)));
      }
      #pragma unroll
      for (int j = 0; j < NREP; ++j) {
        const int n = wc * (NC / 2) + j * 16 + lm;
        const bf16x8 b = *(bf16x8*)((char*)Bs + ((n * 256 + ks * 64 + lk16) ^ ((n & 7) << 4)));
        acc[0][j] = __builtin_amdgcn_mfma_f32_16x16x32_bf16(a[0], b, acc[0][j], 0, 0, 0);
        acc[1][j] = __builtin_amdgcn_mfma_f32_16x16x32_bf16(a[1], b, acc[1][j], 0, 0, 0);
      }
    }
  }
  // ---- store: C row = (lane>>4)*4 + i, col = lane&15 (per frag) ----
  #pragma unroll
  for (int m = 0; m < 2; ++m) {
    const int gr0 = row0 + wr * 32 + m * 16 + (lane >> 4) * 4;
    #pragma unroll
    for (int j = 0; j < NREP; ++j) {
      const int col = wc * (NC / 2) + j * 16 + lm;
      const float cbv = bc ? bc[col] : 0.f;
      #pragma unroll
      for (int i = 0; i < 4; ++i) {
        const int gr = gr0 + i;
        if (gr < M) C[(size_t)gr * NC + col] = acc[m][j][i] + cbv;
      }
    }
  }
}

// ---------------- CSR build ------------------------------------------------------------------
__global__ __launch_bounds__(256) void hist_kernel(
    const int* __restrict__ erow, int* __restrict__ counts, int nE) {
  int e = blockIdx.x * 256 + threadIdx.x;
  if (e < nE) atomicAdd(&counts[erow[e]], 1);
}

__global__ __launch_bounds__(256) void scan1_kernel(
    const int* __restrict__ counts, int* __restrict__ excl,
    int* __restrict__ bsum, int n) {
  __shared__ int lds[256];
  const int t = threadIdx.x;
  const int base = blockIdx.x * SCAN_E + t * 4;
  int4 v = make_int4(0, 0, 0, 0);
  if (base + 3 < n) v = *(const int4*)(counts + base);
  else {
    if (base + 0 < n) v.x = counts[base + 0];
    if (base + 1 < n) v.y = counts[base + 1];
    if (base + 2 < n) v.z = counts[base + 2];
    if (base + 3 < n) v.w = counts[base + 3];
  }
  const int lsum = v.x + v.y + v.z + v.w;
  lds[t] = lsum;
  __syncthreads();
  #pragma unroll
  for (int off = 1; off < 256; off <<= 1) {
    int y = (t >= off) ? lds[t - off] : 0;
    __syncthreads();
    lds[t] += y;
    __syncthreads();
  }
  const int excl_t = lds[t] - lsum;
  if (t == 255) bsum[blockIdx.x] = lds[255];
  int e0 = excl_t, e1 = e0 + v.x, e2 = e1 + v.y, e3 = e2 + v.z;
  if (base + 3 < n) {
    *(int4*)(excl + base) = make_int4(e0, e1, e2, e3);
  } else {
    if (base + 0 < n) excl[base + 0] = e0;
    if (base + 1 < n) excl[base + 1] = e1;
    if (base + 2 < n) excl[base + 2] = e2;
    if (base + 3 < n) excl[base + 3] = e3;
  }
}

__global__ __launch_bounds__(256) void scan2_kernel(
    int* __restrict__ bsum, int* __restrict__ boff, int nb) {
  __shared__ int lds[256];
  const int t = threadIdx.x;
  int v = (t < nb) ? bsum[t] : 0;
  lds[t] = v;
  __syncthreads();
  #pragma unroll
  for (int off = 1; off < 256; off <<= 1) {
    int y = (t >= off) ? lds[t - off] : 0;
    __syncthreads();
    lds[t] += y;
    __syncthreads();
  }
  if (t < nb) boff[t] = lds[t] - v;
}

__global__ __launch_bounds__(256) void scan3_kernel(
    const int* __restrict__ excl, const int* __restrict__ boff,
    int* __restrict__ row_start, int* __restrict__ cursor, int n, int nE) {
  int i = blockIdx.x * 256 + threadIdx.x;
  if (i < n) {
    int rs = excl[i] + boff[i >> 10];
    row_start[i] = rs;
    cursor[i] = rs;
  } else if (i == n) {
    row_start[n] = nE;
  }
}

// ---- pass A: append edges into (bucket, blockIdx&7) segments (XCD-local frontiers) ----------
__global__ __launch_bounds__(256) void scatterA_kernel(
    const int* __restrict__ erow, const int* __restrict__ ecol,
    const float* __restrict__ ew, int* __restrict__ gcurA,
    int4* __restrict__ segs, int nE) {
  int e = blockIdx.x * 256 + threadIdx.x;
  if (e >= nE) return;
  const int r = erow[e];
  const int c = ecol[e];
  const float w = ew[e];
  const int b = r >> 10;
  const int x = blockIdx.x & (NXCD - 1);
  const int seg = x * NBUCK + b;
  int pos = atomicAdd(&gcurA[seg], 1);
  if (pos < SEGCAP)
    segs[(size_t)seg * SEGCAP + pos] = make_int4(r, c, __float_as_int(w), 0);
}

// ---- pass B: one block per bucket; re-scatter into final CSR slots (L2-local window) --------
__global__ __launch_bounds__(512) void scatterB_kernel(
    const int* __restrict__ gcurA, const int4* __restrict__ segs,
    int* __restrict__ cursor, float2* __restrict__ spack) {
  const int b = blockIdx.x;
  const int tid = threadIdx.x;
  for (int x = 0; x < NXCD; ++x) {
    const int seg = x * NBUCK + b;
    int cnt = gcurA[seg];
    if (cnt > SEGCAP) cnt = SEGCAP;
    const int4* s = segs + (size_t)seg * SEGCAP;
    for (int i = tid; i < cnt; i += 512) {
      const int4 t = s[i];
      const int pos = atomicAdd(&cursor[t.x], 1);
      spack[pos] = make_float2(__int_as_float(t.y), __int_as_float(t.z));
    }
  }
}

// ---------------- CSR SpMM: wave per row ----------------------------------------------------
__global__ __launch_bounds__(256) void spmm_csr128(
    const float* __restrict__ feat, const int* __restrict__ row_start,
    const float2* __restrict__ spack, float* __restrict__ out, int M) {
  const int wid = (blockIdx.x * 256 + threadIdx.x) >> 6;
  const int lane = threadIdx.x & 63;
  if (wid >= M) return;
  const int s = row_start[wid], e = row_start[wid + 1];
  float2 acc = make_float2(0.f, 0.f);
  int j = s;
  for (; j + 1 < e; j += 2) {
    const float2 p0 = spack[j];
    const float2 p1 = spack[j + 1];
    const float2 v0 = *(const float2*)(feat + (size_t)__float_as_int(p0.x) * 128 + lane * 2);
    const float2 v1 = *(const float2*)(feat + (size_t)__float_as_int(p1.x) * 128 + lane * 2);
    acc.x = fmaf(v0.x, p0.y, acc.x);
    acc.y = fmaf(v0.y, p0.y, acc.y);
    acc.x = fmaf(v1.x, p1.y, acc.x);
    acc.y = fmaf(v1.y, p1.y, acc.y);
  }
  if (j < e) {
    const float2 p0 = spack[j];
    const float2 v0 = *(const float2*)(feat + (size_t)__float_as_int(p0.x) * 128 + lane * 2);
    acc.x = fmaf(v0.x, p0.y, acc.x);
    acc.y = fmaf(v0.y, p0.y, acc.y);
  }
  *(float2*)(out + (size_t)wid * 128 + lane * 2) = acc;
}

__global__ __launch_bounds__(256) void spmm_csr64(
    const float* __restrict__ feat, const int* __restrict__ row_start,
    const float2* __restrict__ spack, float* __restrict__ out, int M) {
  const int wid = (blockIdx.x * 256 + threadIdx.x) >> 6;
  const int lane = threadIdx.x & 63;
  if (wid >= M) return;
  const int s = row_start[wid], e = row_start[wid + 1];
  float acc = 0.f;
  int j = s;
  for (; j + 1 < e; j += 2) {
    const float2 p0 = spack[j];
    const float2 p1 = spack[j + 1];
    const float v0 = feat[(size_t)__float_as_int(p0.x) * 64 + lane];
    const float v1 = feat[(size_t)__float_as_int(p1.x) * 64 + lane];
    acc = fmaf(v0, p0.y, acc);
    acc = fmaf(v1, p1.y, acc);
  }
  if (j < e) {
    const float2 p0 = spack[j];
    acc = fmaf(feat[(size_t)__float_as_int(p0.x) * 64 + lane], p0.y, acc);
  }
  out[(size_t)wid * 64 + lane] = acc;
}

// ---------------- head ----------------------------------------------------------------------
__global__ __launch_bounds__(256) void final_kernel(
    const float* __restrict__ s2, const float* __restrict__ pred_w,
    const float* __restrict__ pred_b, const float* __restrict__ b2,
    float* __restrict__ out, int M) {
  __shared__ float pw[512];
  __shared__ float pb[8];
  __shared__ float bb[64];
  const int tid = threadIdx.x;
  for (int i = tid; i < 512; i += 256) pw[i] = pred_w[i];
  if (tid < 8) pb[tid] = pred_b[tid];
  if (tid < 64) bb[tid] = b2[tid];
  __syncthreads();
  const int node = blockIdx.x * 32 + (tid >> 3);
  const int c = tid & 7;
  if (node >= M) return;
  const float* row = s2 + (size_t)node * 64;
  float acc = pb[c];
  #pragma unroll 8
  for (int k = 0; k < 64; ++k)
    acc = fmaf(fmaxf(row[k] + bb[k], 0.f), pw[c * 64 + k], acc);
  out[node * 8 + c] = acc;
}

// ---------------- zero fill ------------------------------------------------------------------
__global__ void zero_kernel(float4* __restrict__ p, int n4) {
  int i = blockIdx.x * blockDim.x + threadIdx.x;
  const int stride = gridDim.x * blockDim.x;
  for (; i < n4; i += stride) p[i] = make_float4(0.f, 0.f, 0.f, 0.f);
}

extern "C" void kernel_launch(void* const* d_in, const int* in_sizes, int n_in,
                              void* d_out, int out_size, void* d_ws, size_t ws_size,
                              hipStream_t stream) {
  const float* feat0  = (const float*)d_in[0];
  const float* feat1  = (const float*)d_in[1];
  const float* fc0_w  = (const float*)d_in[2];
  const float* fc0_b  = (const float*)d_in[3];
  const float* fc1_w  = (const float*)d_in[4];
  const float* fc1_b  = (const float*)d_in[5];
  const float* W1     = (const float*)d_in[6];
  const float* b1     = (const float*)d_in[7];
  const float* W2     = (const float*)d_in[8];
  const float* b2     = (const float*)d_in[9];
  const float* pred_w = (const float*)d_in[10];
  const float* pred_b = (const float*)d_in[11];
  const int*   erow   = (const int*)d_in[12];
  const int*   ecol   = (const int*)d_in[13];
  const float* ew     = (const float*)d_in[14];
  float* out = (float*)d_out;
  const int nE = in_sizes[12];
  const int N = N_NODES;

  char* ws = (char*)d_ws;
  size_t off = 0;
  unsigned short* M0T = (unsigned short*)(ws + off); off += 32768;
  unsigned short* M1T = (unsigned short*)(ws + off); off += 65536;
  unsigned short* W2T = (unsigned short*)(ws + off); off += 16384;
  float* cb = (float*)(ws + off); off += 1024;
  int* counts = (int*)(ws + off); off += 400000;            // N ints
  int* gcurA  = (int*)(ws + off); off += 3136;              // 784 ints (zeroed w/ counts)
  int* excl      = (int*)(ws + off); off += 400000;
  int* row_start = (int*)(ws + off); off += 400016;
  int* cursor    = (int*)(ws + off); off += 400000;
  int* bsum      = (int*)(ws + off); off += 512;
  int* boff      = (int*)(ws + off); off += 2512;           // pad to 16B
  int4* segs     = (int4*)(ws + off); off += (size_t)NXCD * NBUCK * SEGCAP * 16;  // 38.5 MB
  float2* spack  = (float2*)(ws + off); off += (size_t)nE * 8;
  float* bufA = (float*)(ws + off); off += (size_t)N * 128 * 4;
  float* bufB = (float*)(ws + off); off += (size_t)N * 128 * 4;
  float* h1 = bufA;
  float* s1 = bufB;
  float* h2 = bufA;
  float* s2 = bufB;

  const int nb1 = (N + SCAN_E - 1) / SCAN_E;  // 98

  // ---- CSR build ----
  hipLaunchKernelGGL(zero_kernel, dim3(128), dim3(256), 0, stream,
                     (float4*)counts, (400000 + 3136) / 16);
  hipLaunchKernelGGL(hist_kernel, dim3((nE + 255) / 256), dim3(256), 0, stream,
                     erow, counts, nE);
  hipLaunchKernelGGL(scan1_kernel, dim3(nb1), dim3(256), 0, stream,
                     counts, excl, bsum, N);
  hipLaunchKernelGGL(scan2_kernel, dim3(1), dim3(256), 0, stream, bsum, boff, nb1);
  hipLaunchKernelGGL(scan3_kernel, dim3((N + 256) / 256), dim3(256), 0, stream,
                     excl, boff, row_start, cursor, N, nE);
  hipLaunchKernelGGL(scatterA_kernel, dim3((nE + 255) / 256), dim3(256), 0, stream,
                     erow, ecol, ew, gcurA, segs, nE);
  hipLaunchKernelGGL(scatterB_kernel, dim3(NBUCK), dim3(512), 0, stream,
                     gcurA, segs, cursor, spack);

  // ---- dense pipeline ----
  hipLaunchKernelGGL(prep_small_kernel, dim3(225), dim3(256), 0, stream,
                     fc0_w, fc1_w, fc0_b, fc1_b, W1, W2, M0T, M1T, W2T, cb);
  hipLaunchKernelGGL((mfma_gemm_kernel<128, 128, false>), dim3((N_TYPE + 63) / 64), dim3(256),
                     0, stream, feat0, M0T, nullptr, cb, h1, N_TYPE);
  hipLaunchKernelGGL((mfma_gemm_kernel<128, 256, false>), dim3((N_TYPE + 63) / 64), dim3(256),
                     0, stream, feat1, M1T, nullptr, cb + 128,
                     h1 + (size_t)N_TYPE * 128, N_TYPE);
  // s1 = adj @ h1
  hipLaunchKernelGGL(spmm_csr128, dim3((N * 64 + 255) / 256), dim3(256), 0, stream,
                     h1, row_start, spack, s1, N);
  // h2 = relu(s1 + b1) @ W2
  hipLaunchKernelGGL((mfma_gemm_kernel<64, 128, true>), dim3((N + 63) / 64), dim3(256),
                     0, stream, s1, W2T, b1, nullptr, h2, N);
  // s2 = adj @ h2
  hipLaunchKernelGGL(spmm_csr64, dim3((N * 64 + 255) / 256), dim3(256), 0, stream,
                     h2, row_start, spack, s2, N);
  // head
  hipLaunchKernelGGL(final_kernel, dim3((N + 31) / 32), dim3(256), 0, stream,
                     s2, pred_w, pred_b, b2, out, N);
}

// Round 4
// 435.675 us; speedup vs baseline: 1.9776x; 1.9776x over previous
//
#include <hip/hip_runtime.h>
#include <hip/hip_bf16.h>

#define N_NODES 100000
#define N_TYPE  50000
#define SCAN_E  1024

typedef short bf16x8 __attribute__((ext_vector_type(8)));
typedef float f32x4  __attribute__((ext_vector_type(4)));
typedef unsigned short u16x4 __attribute__((ext_vector_type(4)));

__device__ inline unsigned short f2bf(float f) {
  union { float f; unsigned u; } x; x.f = f;
  unsigned r = (x.u + 0x7fff + ((x.u >> 16) & 1)) >> 16;  // RNE
  return (unsigned short)r;
}
__device__ inline float bf2f(unsigned short h) {
  union { unsigned u; float f; } x; x.u = ((unsigned)h) << 16;
  return x.f;
}

// ---------------- prep: bf16 transposed weights + combined bias ------------------------------
__global__ __launch_bounds__(256) void prep_small_kernel(
    const float* __restrict__ fc0_w, const float* __restrict__ fc1_w,
    const float* __restrict__ fc0_b, const float* __restrict__ fc1_b,
    const float* __restrict__ W1, const float* __restrict__ W2,
    unsigned short* __restrict__ M0T, unsigned short* __restrict__ M1T,
    unsigned short* __restrict__ W2T, float* __restrict__ cb) {
  int idx = blockIdx.x * 256 + threadIdx.x;
  if (idx < 16384) {                       // M0T[n=128][k=128]
    int i = idx >> 7, j = idx & 127;
    float s = 0.f;
    #pragma unroll 4
    for (int o = 0; o < 128; ++o) s = fmaf(fc0_w[o * 128 + i], W1[o * 128 + j], s);
    M0T[j * 128 + i] = f2bf(s);
  } else if (idx < 49152) {                // M1T[n=128][k=256]
    int r = idx - 16384;
    int i = r >> 7, j = r & 127;
    float s = 0.f;
    #pragma unroll 4
    for (int o = 0; o < 128; ++o) s = fmaf(fc1_w[o * 256 + i], W1[o * 128 + j], s);
    M1T[j * 256 + i] = f2bf(s);
  } else if (idx < 57344) {                // W2T[n=64][k=128]
    int r = idx - 49152;
    int k = r >> 6, n = r & 63;
    W2T[n * 128 + k] = f2bf(W2[k * 64 + n]);
  } else if (idx < 57600) {                // cb[256]
    int r = idx - 57344;
    int t = r >> 7, j = r & 127;
    const float* bb = t ? fc1_b : fc0_b;
    float s = 0.f;
    for (int o = 0; o < 128; ++o) s = fmaf(bb[o], W1[o * 128 + j], s);
    cb[r] = s;
  }
}

// ---------------- bf16 MFMA GEMM: C[M][NC] = act(A[M][KTOT]) @ BT^T (+bc) --------------------
// A fp32 [M][KTOT]; BT bf16 [NC][KTOT]. Output bf16 (OUT_BF16) or fp32.
template <int NC, int KTOT, bool RELU_BIAS, bool OUT_BF16>
__global__ __launch_bounds__(256) void mfma_gemm_kernel(
    const float* __restrict__ A, const unsigned short* __restrict__ BT,
    const float* __restrict__ bk, const float* __restrict__ bc,
    void* __restrict__ Cout, int M) {
  constexpr int NREP = NC / 32;
  __shared__ unsigned short As[64 * 128];
  __shared__ unsigned short Bs[NC * 128];

  const int tid = threadIdx.x;
  const int row0 = blockIdx.x * 64;
  const int wave = tid >> 6, lane = tid & 63;
  const int wr = wave >> 1, wc = wave & 1;
  const int lm = lane & 15;
  const int lk16 = (lane >> 4) * 16;

  f32x4 acc[2][NREP];
  #pragma unroll
  for (int i = 0; i < 2; ++i)
    #pragma unroll
    for (int j = 0; j < NREP; ++j) acc[i][j] = (f32x4){0.f, 0.f, 0.f, 0.f};

  for (int kc = 0; kc < KTOT; kc += 128) {
    if (kc) __syncthreads();
    // stage A: fp32 -> bf16, XOR-swizzled rows
    {
      const int r = tid >> 2;
      const int cg = tid & 3;
      int gr = row0 + r; if (gr > M - 1) gr = M - 1;
      const float* arow = A + (size_t)gr * KTOT + kc;
      char* asrow = (char*)As + r * 256;
      const int swz = (r & 7) << 4;
      #pragma unroll
      for (int i = 0; i < 8; ++i) {
        const int c = i * 4 + cg;
        float4 v = *(const float4*)(arow + c * 4);
        if (RELU_BIAS) {
          const float4 b = *(const float4*)(bk + kc + c * 4);
          v.x = fmaxf(v.x + b.x, 0.f);
          v.y = fmaxf(v.y + b.y, 0.f);
          v.z = fmaxf(v.z + b.z, 0.f);
          v.w = fmaxf(v.w + b.w, 0.f);
        }
        u16x4 q = {f2bf(v.x), f2bf(v.y), f2bf(v.z), f2bf(v.w)};
        *(u16x4*)(asrow + ((c * 8) ^ swz)) = q;
      }
    }
    // stage B: bf16 copy, swizzled
    {
      constexpr int CHUNKS = NC * 16;
      #pragma unroll
      for (int i = 0; i < CHUNKS / 256; ++i) {
        const int id = i * 256 + tid;
        const int n = id >> 4, k16 = id & 15;
        const uint4 w = *(const uint4*)((const char*)BT + ((size_t)n * KTOT + kc) * 2 + k16 * 16);
        *(uint4*)((char*)Bs + ((n * 256 + k16 * 16) ^ ((n & 7) << 4))) = w;
      }
    }
    __syncthreads();
    #pragma unroll
    for (int ks = 0; ks < 4; ++ks) {
      bf16x8 a[2];
      #pragma unroll
      for (int m = 0; m < 2; ++m) {
        const int r = wr * 32 + m * 16 + lm;
        a[m] = *(bf16x8*)((char*)As + ((r * 256 + ks * 64 + lk16) ^ ((r & 7) << 4)));
      }
      #pragma unroll
      for (int j = 0; j < NREP; ++j) {
        const int n = wc * (NC / 2) + j * 16 + lm;
        const bf16x8 b = *(bf16x8*)((char*)Bs + ((n * 256 + ks * 64 + lk16) ^ ((n & 7) << 4)));
        acc[0][j] = __builtin_amdgcn_mfma_f32_16x16x32_bf16(a[0], b, acc[0][j], 0, 0, 0);
        acc[1][j] = __builtin_amdgcn_mfma_f32_16x16x32_bf16(a[1], b, acc[1][j], 0, 0, 0);
      }
    }
  }
  #pragma unroll
  for (int m = 0; m < 2; ++m) {
    const int gr0 = row0 + wr * 32 + m * 16 + (lane >> 4) * 4;
    #pragma unroll
    for (int j = 0; j < NREP; ++j) {
      const int col = wc * (NC / 2) + j * 16 + lm;
      const float cbv = bc ? bc[col] : 0.f;
      #pragma unroll
      for (int i = 0; i < 4; ++i) {
        const int gr = gr0 + i;
        if (gr < M) {
          const float val = acc[m][j][i] + cbv;
          if (OUT_BF16)
            ((unsigned short*)Cout)[(size_t)gr * NC + col] = f2bf(val);
          else
            ((float*)Cout)[(size_t)gr * NC + col] = val;
        }
      }
    }
  }
}

// ---------------- CSR build ------------------------------------------------------------------
__global__ __launch_bounds__(256) void hist_kernel(
    const int* __restrict__ erow, int* __restrict__ counts, int nE) {
  int e = blockIdx.x * 256 + threadIdx.x;
  if (e < nE) atomicAdd(&counts[erow[e]], 1);
}

__global__ __launch_bounds__(256) void scan1_kernel(
    const int* __restrict__ counts, int* __restrict__ excl,
    int* __restrict__ bsum, int n) {
  __shared__ int lds[256];
  const int t = threadIdx.x;
  const int base = blockIdx.x * SCAN_E + t * 4;
  int4 v = make_int4(0, 0, 0, 0);
  if (base + 3 < n) v = *(const int4*)(counts + base);
  else {
    if (base + 0 < n) v.x = counts[base + 0];
    if (base + 1 < n) v.y = counts[base + 1];
    if (base + 2 < n) v.z = counts[base + 2];
    if (base + 3 < n) v.w = counts[base + 3];
  }
  const int lsum = v.x + v.y + v.z + v.w;
  lds[t] = lsum;
  __syncthreads();
  #pragma unroll
  for (int off = 1; off < 256; off <<= 1) {
    int y = (t >= off) ? lds[t - off] : 0;
    __syncthreads();
    lds[t] += y;
    __syncthreads();
  }
  const int excl_t = lds[t] - lsum;
  if (t == 255) bsum[blockIdx.x] = lds[255];
  int e0 = excl_t, e1 = e0 + v.x, e2 = e1 + v.y, e3 = e2 + v.z;
  if (base + 3 < n) {
    *(int4*)(excl + base) = make_int4(e0, e1, e2, e3);
  } else {
    if (base + 0 < n) excl[base + 0] = e0;
    if (base + 1 < n) excl[base + 1] = e1;
    if (base + 2 < n) excl[base + 2] = e2;
    if (base + 3 < n) excl[base + 3] = e3;
  }
}

__global__ __launch_bounds__(256) void scan2_kernel(
    int* __restrict__ bsum, int* __restrict__ boff, int nb) {
  __shared__ int lds[256];
  const int t = threadIdx.x;
  int v = (t < nb) ? bsum[t] : 0;
  lds[t] = v;
  __syncthreads();
  #pragma unroll
  for (int off = 1; off < 256; off <<= 1) {
    int y = (t >= off) ? lds[t - off] : 0;
    __syncthreads();
    lds[t] += y;
    __syncthreads();
  }
  if (t < nb) boff[t] = lds[t] - v;
}

__global__ __launch_bounds__(256) void scan3_kernel(
    const int* __restrict__ excl, const int* __restrict__ boff,
    int* __restrict__ row_start, int* __restrict__ cursor, int n, int nE) {
  int i = blockIdx.x * 256 + threadIdx.x;
  if (i < n) {
    int rs = excl[i] + boff[i >> 10];
    row_start[i] = rs;
    cursor[i] = rs;
  } else if (i == n) {
    row_start[n] = nE;
  }
}

__global__ __launch_bounds__(256) void scatter_kernel(
    const int* __restrict__ erow, const int* __restrict__ ecol,
    const float* __restrict__ ew, int* __restrict__ cursor,
    float2* __restrict__ spack, int nE) {
  int e = blockIdx.x * 256 + threadIdx.x;
  if (e >= nE) return;
  int r = erow[e];
  int pos = atomicAdd(&cursor[r], 1);
  spack[pos] = make_float2(__int_as_float(ecol[e]), ew[e]);
}

// ---------------- CSR SpMM (bf16 gather, fp32 accumulate) ------------------------------------
// F=128: one wave per row; lane covers 2 cols (4B bf16x2 load).
__global__ __launch_bounds__(256) void spmm_csr128_bf16(
    const unsigned short* __restrict__ feat, const int* __restrict__ row_start,
    const float2* __restrict__ spack, float* __restrict__ out, int M) {
  const int wid = (blockIdx.x * 256 + threadIdx.x) >> 6;
  const int lane = threadIdx.x & 63;
  if (wid >= M) return;
  const int s = row_start[wid], e = row_start[wid + 1];
  float2 acc = make_float2(0.f, 0.f);
  int j = s;
  for (; j + 1 < e; j += 2) {
    const float2 p0 = spack[j];
    const float2 p1 = spack[j + 1];
    const ushort2 v0 = *(const ushort2*)(feat + (size_t)__float_as_int(p0.x) * 128 + lane * 2);
    const ushort2 v1 = *(const ushort2*)(feat + (size_t)__float_as_int(p1.x) * 128 + lane * 2);
    acc.x = fmaf(bf2f(v0.x), p0.y, acc.x);
    acc.y = fmaf(bf2f(v0.y), p0.y, acc.y);
    acc.x = fmaf(bf2f(v1.x), p1.y, acc.x);
    acc.y = fmaf(bf2f(v1.y), p1.y, acc.y);
  }
  if (j < e) {
    const float2 p0 = spack[j];
    const ushort2 v0 = *(const ushort2*)(feat + (size_t)__float_as_int(p0.x) * 128 + lane * 2);
    acc.x = fmaf(bf2f(v0.x), p0.y, acc.x);
    acc.y = fmaf(bf2f(v0.y), p0.y, acc.y);
  }
  *(float2*)(out + (size_t)wid * 128 + lane * 2) = acc;
}

// F=64: 32 lanes per row (2 rows per wave); lane covers 2 cols.
__global__ __launch_bounds__(256) void spmm_csr64_bf16(
    const unsigned short* __restrict__ feat, const int* __restrict__ row_start,
    const float2* __restrict__ spack, float* __restrict__ out, int M) {
  const int wid = (blockIdx.x * 256 + threadIdx.x) >> 5;
  const int lane = threadIdx.x & 31;
  if (wid >= M) return;
  const int s = row_start[wid], e = row_start[wid + 1];
  float2 acc = make_float2(0.f, 0.f);
  int j = s;
  for (; j + 1 < e; j += 2) {
    const float2 p0 = spack[j];
    const float2 p1 = spack[j + 1];
    const ushort2 v0 = *(const ushort2*)(feat + (size_t)__float_as_int(p0.x) * 64 + lane * 2);
    const ushort2 v1 = *(const ushort2*)(feat + (size_t)__float_as_int(p1.x) * 64 + lane * 2);
    acc.x = fmaf(bf2f(v0.x), p0.y, acc.x);
    acc.y = fmaf(bf2f(v0.y), p0.y, acc.y);
    acc.x = fmaf(bf2f(v1.x), p1.y, acc.x);
    acc.y = fmaf(bf2f(v1.y), p1.y, acc.y);
  }
  if (j < e) {
    const float2 p0 = spack[j];
    const ushort2 v0 = *(const ushort2*)(feat + (size_t)__float_as_int(p0.x) * 64 + lane * 2);
    acc.x = fmaf(bf2f(v0.x), p0.y, acc.x);
    acc.y = fmaf(bf2f(v0.y), p0.y, acc.y);
  }
  *(float2*)(out + (size_t)wid * 64 + lane * 2) = acc;
}

// ---------------- head ----------------------------------------------------------------------
__global__ __launch_bounds__(256) void final_kernel(
    const float* __restrict__ s2, const float* __restrict__ pred_w,
    const float* __restrict__ pred_b, const float* __restrict__ b2,
    float* __restrict__ out, int M) {
  __shared__ float pw[512];
  __shared__ float pb[8];
  __shared__ float bb[64];
  const int tid = threadIdx.x;
  for (int i = tid; i < 512; i += 256) pw[i] = pred_w[i];
  if (tid < 8) pb[tid] = pred_b[tid];
  if (tid < 64) bb[tid] = b2[tid];
  __syncthreads();
  const int node = blockIdx.x * 32 + (tid >> 3);
  const int c = tid & 7;
  if (node >= M) return;
  const float* row = s2 + (size_t)node * 64;
  float acc = pb[c];
  #pragma unroll 8
  for (int k = 0; k < 64; ++k)
    acc = fmaf(fmaxf(row[k] + bb[k], 0.f), pw[c * 64 + k], acc);
  out[node * 8 + c] = acc;
}

// ---------------- zero fill ------------------------------------------------------------------
__global__ void zero_kernel(float4* __restrict__ p, int n4) {
  int i = blockIdx.x * blockDim.x + threadIdx.x;
  const int stride = gridDim.x * blockDim.x;
  for (; i < n4; i += stride) p[i] = make_float4(0.f, 0.f, 0.f, 0.f);
}

extern "C" void kernel_launch(void* const* d_in, const int* in_sizes, int n_in,
                              void* d_out, int out_size, void* d_ws, size_t ws_size,
                              hipStream_t stream) {
  const float* feat0  = (const float*)d_in[0];
  const float* feat1  = (const float*)d_in[1];
  const float* fc0_w  = (const float*)d_in[2];
  const float* fc0_b  = (const float*)d_in[3];
  const float* fc1_w  = (const float*)d_in[4];
  const float* fc1_b  = (const float*)d_in[5];
  const float* W1     = (const float*)d_in[6];
  const float* b1     = (const float*)d_in[7];
  const float* W2     = (const float*)d_in[8];
  const float* b2     = (const float*)d_in[9];
  const float* pred_w = (const float*)d_in[10];
  const float* pred_b = (const float*)d_in[11];
  const int*   erow   = (const int*)d_in[12];
  const int*   ecol   = (const int*)d_in[13];
  const float* ew     = (const float*)d_in[14];
  float* out = (float*)d_out;
  const int nE = in_sizes[12];
  const int N = N_NODES;

  char* ws = (char*)d_ws;
  size_t off = 0;
  unsigned short* M0T = (unsigned short*)(ws + off); off += 32768;
  unsigned short* M1T = (unsigned short*)(ws + off); off += 65536;
  unsigned short* W2T = (unsigned short*)(ws + off); off += 16384;
  float* cb = (float*)(ws + off); off += 1024;
  int* counts    = (int*)(ws + off); off += 400000;
  int* excl      = (int*)(ws + off); off += 400000;
  int* row_start = (int*)(ws + off); off += 400016;
  int* cursor    = (int*)(ws + off); off += 400000;
  int* bsum      = (int*)(ws + off); off += 512;
  int* boff      = (int*)(ws + off); off += 2512;
  float2* spack  = (float2*)(ws + off); off += (size_t)nE * 8;            // 12.8 MB
  unsigned short* h = (unsigned short*)(ws + off); off += (size_t)N * 128 * 2;  // 25.6 MB
  float* s = (float*)(ws + off); off += (size_t)N * 128 * 4;              // 51.2 MB

  const int nb1 = (N + SCAN_E - 1) / SCAN_E;  // 98

  // ---- CSR build ----
  hipLaunchKernelGGL(zero_kernel, dim3(128), dim3(256), 0, stream,
                     (float4*)counts, 400000 / 16);
  hipLaunchKernelGGL(hist_kernel, dim3((nE + 255) / 256), dim3(256), 0, stream,
                     erow, counts, nE);
  hipLaunchKernelGGL(scan1_kernel, dim3(nb1), dim3(256), 0, stream,
                     counts, excl, bsum, N);
  hipLaunchKernelGGL(scan2_kernel, dim3(1), dim3(256), 0, stream, bsum, boff, nb1);
  hipLaunchKernelGGL(scan3_kernel, dim3((N + 256) / 256), dim3(256), 0, stream,
                     excl, boff, row_start, cursor, N, nE);
  hipLaunchKernelGGL(scatter_kernel, dim3((nE + 255) / 256), dim3(256), 0, stream,
                     erow, ecol, ew, cursor, spack, nE);

  // ---- dense pipeline ----
  hipLaunchKernelGGL(prep_small_kernel, dim3(225), dim3(256), 0, stream,
                     fc0_w, fc1_w, fc0_b, fc1_b, W1, W2, M0T, M1T, W2T, cb);
  // h1 = bf16(feat0 @ M0 + cb0) ; h1 upper half from feat1
  hipLaunchKernelGGL((mfma_gemm_kernel<128, 128, false, true>), dim3((N_TYPE + 63) / 64),
                     dim3(256), 0, stream, feat0, M0T, nullptr, cb, (void*)h, N_TYPE);
  hipLaunchKernelGGL((mfma_gemm_kernel<128, 256, false, true>), dim3((N_TYPE + 63) / 64),
                     dim3(256), 0, stream, feat1, M1T, nullptr, cb + 128,
                     (void*)(h + (size_t)N_TYPE * 128), N_TYPE);
  // s1 = adj @ h1  (fp32)
  hipLaunchKernelGGL(spmm_csr128_bf16, dim3((N * 64 + 255) / 256), dim3(256), 0, stream,
                     h, row_start, spack, s, N);
  // h2 = bf16(relu(s1 + b1) @ W2)
  hipLaunchKernelGGL((mfma_gemm_kernel<64, 128, true, true>), dim3((N + 63) / 64),
                     dim3(256), 0, stream, s, W2T, b1, nullptr, (void*)h, N);
  // s2 = adj @ h2  (fp32)
  hipLaunchKernelGGL(spmm_csr64_bf16, dim3((N * 32 + 255) / 256), dim3(256), 0, stream,
                     h, row_start, spack, s, N);
  // head
  hipLaunchKernelGGL(final_kernel, dim3((N + 31) / 32), dim3(256), 0, stream,
                     s, pred_w, pred_b, b2, out, N);
}

// Round 5
// 344.504 us; speedup vs baseline: 2.5010x; 1.2646x over previous
//
#include <hip/hip_runtime.h>
#include <hip/hip_bf16.h>

#define N_NODES 100000
#define N_TYPE  50000
#define SCAN_E  1024
#define NB1     192        // part1 blocks
#define EPB1    8334       // edges per part1 block (192*8334 >= 1.6M)
#define NBUCK2  196        // ceil(100000/512) row buckets

typedef short bf16x8 __attribute__((ext_vector_type(8)));
typedef float f32x4  __attribute__((ext_vector_type(4)));
typedef unsigned short u16x4 __attribute__((ext_vector_type(4)));

__device__ inline unsigned short f2bf(float f) {
  union { float f; unsigned u; } x; x.f = f;
  unsigned r = (x.u + 0x7fff + ((x.u >> 16) & 1)) >> 16;  // RNE
  return (unsigned short)r;
}
__device__ inline float bf2f(unsigned short h) {
  union { unsigned u; float f; } x; x.u = ((unsigned)h) << 16;
  return x.f;
}

// ---------------- prep: bf16 transposed weights + combined bias ------------------------------
__global__ __launch_bounds__(256) void prep_small_kernel(
    const float* __restrict__ fc0_w, const float* __restrict__ fc1_w,
    const float* __restrict__ fc0_b, const float* __restrict__ fc1_b,
    const float* __restrict__ W1, const float* __restrict__ W2,
    unsigned short* __restrict__ M0T, unsigned short* __restrict__ M1T,
    unsigned short* __restrict__ W2T, float* __restrict__ cb) {
  int idx = blockIdx.x * 256 + threadIdx.x;
  if (idx < 16384) {                       // M0T[n=128][k=128]
    int i = idx >> 7, j = idx & 127;
    float s = 0.f;
    #pragma unroll 4
    for (int o = 0; o < 128; ++o) s = fmaf(fc0_w[o * 128 + i], W1[o * 128 + j], s);
    M0T[j * 128 + i] = f2bf(s);
  } else if (idx < 49152) {                // M1T[n=128][k=256]
    int r = idx - 16384;
    int i = r >> 7, j = r & 127;
    float s = 0.f;
    #pragma unroll 4
    for (int o = 0; o < 128; ++o) s = fmaf(fc1_w[o * 256 + i], W1[o * 128 + j], s);
    M1T[j * 256 + i] = f2bf(s);
  } else if (idx < 57344) {                // W2T[n=64][k=128]
    int r = idx - 49152;
    int k = r >> 6, n = r & 63;
    W2T[n * 128 + k] = f2bf(W2[k * 64 + n]);
  } else if (idx < 57600) {                // cb[256]
    int r = idx - 57344;
    int t = r >> 7, j = r & 127;
    const float* bb = t ? fc1_b : fc0_b;
    float s = 0.f;
    for (int o = 0; o < 128; ++o) s = fmaf(bb[o], W1[o * 128 + j], s);
    cb[r] = s;
  }
}

// ---------------- bf16 MFMA GEMM -------------------------------------------------------------
template <int NC, int KTOT, bool RELU_BIAS, bool OUT_BF16>
__global__ __launch_bounds__(256) void mfma_gemm_kernel(
    const float* __restrict__ A, const unsigned short* __restrict__ BT,
    const float* __restrict__ bk, const float* __restrict__ bc,
    void* __restrict__ Cout, int M) {
  constexpr int NREP = NC / 32;
  __shared__ unsigned short As[64 * 128];
  __shared__ unsigned short Bs[NC * 128];

  const int tid = threadIdx.x;
  const int row0 = blockIdx.x * 64;
  const int wave = tid >> 6, lane = tid & 63;
  const int wr = wave >> 1, wc = wave & 1;
  const int lm = lane & 15;
  const int lk16 = (lane >> 4) * 16;

  f32x4 acc[2][NREP];
  #pragma unroll
  for (int i = 0; i < 2; ++i)
    #pragma unroll
    for (int j = 0; j < NREP; ++j) acc[i][j] = (f32x4){0.f, 0.f, 0.f, 0.f};

  for (int kc = 0; kc < KTOT; kc += 128) {
    if (kc) __syncthreads();
    {
      const int r = tid >> 2;
      const int cg = tid & 3;
      int gr = row0 + r; if (gr > M - 1) gr = M - 1;
      const float* arow = A + (size_t)gr * KTOT + kc;
      char* asrow = (char*)As + r * 256;
      const int swz = (r & 7) << 4;
      #pragma unroll
      for (int i = 0; i < 8; ++i) {
        const int c = i * 4 + cg;
        float4 v = *(const float4*)(arow + c * 4);
        if (RELU_BIAS) {
          const float4 b = *(const float4*)(bk + kc + c * 4);
          v.x = fmaxf(v.x + b.x, 0.f);
          v.y = fmaxf(v.y + b.y, 0.f);
          v.z = fmaxf(v.z + b.z, 0.f);
          v.w = fmaxf(v.w + b.w, 0.f);
        }
        u16x4 q = {f2bf(v.x), f2bf(v.y), f2bf(v.z), f2bf(v.w)};
        *(u16x4*)(asrow + ((c * 8) ^ swz)) = q;
      }
    }
    {
      constexpr int CHUNKS = NC * 16;
      #pragma unroll
      for (int i = 0; i < CHUNKS / 256; ++i) {
        const int id = i * 256 + tid;
        const int n = id >> 4, k16 = id & 15;
        const uint4 w = *(const uint4*)((const char*)BT + ((size_t)n * KTOT + kc) * 2 + k16 * 16);
        *(uint4*)((char*)Bs + ((n * 256 + k16 * 16) ^ ((n & 7) << 4))) = w;
      }
    }
    __syncthreads();
    #pragma unroll
    for (int ks = 0; ks < 4; ++ks) {
      bf16x8 a[2];
      #pragma unroll
      for (int m = 0; m < 2; ++m) {
        const int r = wr * 32 + m * 16 + lm;
        a[m] = *(bf16x8*)((char*)As + ((r * 256 + ks * 64 + lk16) ^ ((r & 7) << 4)));
      }
      #pragma unroll
      for (int j = 0; j < NREP; ++j) {
        const int n = wc * (NC / 2) + j * 16 + lm;
        const bf16x8 b = *(bf16x8*)((char*)Bs + ((n * 256 + ks * 64 + lk16) ^ ((n & 7) << 4)));
        acc[0][j] = __builtin_amdgcn_mfma_f32_16x16x32_bf16(a[0], b, acc[0][j], 0, 0, 0);
        acc[1][j] = __builtin_amdgcn_mfma_f32_16x16x32_bf16(a[1], b, acc[1][j], 0, 0, 0);
      }
    }
  }
  #pragma unroll
  for (int m = 0; m < 2; ++m) {
    const int gr0 = row0 + wr * 32 + m * 16 + (lane >> 4) * 4;
    #pragma unroll
    for (int j = 0; j < NREP; ++j) {
      const int col = wc * (NC / 2) + j * 16 + lm;
      const float cbv = bc ? bc[col] : 0.f;
      #pragma unroll
      for (int i = 0; i < 4; ++i) {
        const int gr = gr0 + i;
        if (gr < M) {
          const float val = acc[m][j][i] + cbv;
          if (OUT_BF16)
            ((unsigned short*)Cout)[(size_t)gr * NC + col] = f2bf(val);
          else
            ((float*)Cout)[(size_t)gr * NC + col] = val;
        }
      }
    }
  }
}

// ---------------- CSR build ------------------------------------------------------------------
__global__ __launch_bounds__(256) void hist_kernel(
    const int* __restrict__ erow, int* __restrict__ counts, int nE) {
  int e = blockIdx.x * 256 + threadIdx.x;
  if (e < nE) atomicAdd(&counts[erow[e]], 1);
}

__global__ __launch_bounds__(256) void scan1_kernel(
    const int* __restrict__ counts, int* __restrict__ excl,
    int* __restrict__ bsum, int n) {
  __shared__ int lds[256];
  const int t = threadIdx.x;
  const int base = blockIdx.x * SCAN_E + t * 4;
  int4 v = make_int4(0, 0, 0, 0);
  if (base + 3 < n) v = *(const int4*)(counts + base);
  else {
    if (base + 0 < n) v.x = counts[base + 0];
    if (base + 1 < n) v.y = counts[base + 1];
    if (base + 2 < n) v.z = counts[base + 2];
    if (base + 3 < n) v.w = counts[base + 3];
  }
  const int lsum = v.x + v.y + v.z + v.w;
  lds[t] = lsum;
  __syncthreads();
  #pragma unroll
  for (int off = 1; off < 256; off <<= 1) {
    int y = (t >= off) ? lds[t - off] : 0;
    __syncthreads();
    lds[t] += y;
    __syncthreads();
  }
  const int excl_t = lds[t] - lsum;
  if (t == 255) bsum[blockIdx.x] = lds[255];
  int e0 = excl_t, e1 = e0 + v.x, e2 = e1 + v.y, e3 = e2 + v.z;
  if (base + 3 < n) {
    *(int4*)(excl + base) = make_int4(e0, e1, e2, e3);
  } else {
    if (base + 0 < n) excl[base + 0] = e0;
    if (base + 1 < n) excl[base + 1] = e1;
    if (base + 2 < n) excl[base + 2] = e2;
    if (base + 3 < n) excl[base + 3] = e3;
  }
}

__global__ __launch_bounds__(256) void scan2_kernel(
    int* __restrict__ bsum, int* __restrict__ boff, int nb) {
  __shared__ int lds[256];
  const int t = threadIdx.x;
  int v = (t < nb) ? bsum[t] : 0;
  lds[t] = v;
  __syncthreads();
  #pragma unroll
  for (int off = 1; off < 256; off <<= 1) {
    int y = (t >= off) ? lds[t - off] : 0;
    __syncthreads();
    lds[t] += y;
    __syncthreads();
  }
  if (t < nb) boff[t] = lds[t] - v;
}

// row_start + init padded bucket cursors (bcur[b*16] = row_start[b*512])
__global__ __launch_bounds__(256) void scan3_kernel(
    const int* __restrict__ excl, const int* __restrict__ boff,
    int* __restrict__ row_start, int* __restrict__ bcur, int n, int nE) {
  int i = blockIdx.x * 256 + threadIdx.x;
  if (i < n) {
    int rs = excl[i] + boff[i >> 10];
    row_start[i] = rs;
    if ((i & 511) == 0) bcur[(i >> 9) * 16] = rs;
  } else if (i == n) {
    row_start[n] = nE;
  }
}

// ---- part1: partition edges into 512-row buckets; contiguous run writes per (block,bucket) --
__global__ __launch_bounds__(512) void part1_kernel(
    const int* __restrict__ erow, const int* __restrict__ ecol,
    const float* __restrict__ ew, int* __restrict__ bcur,
    uint2* __restrict__ tmp, int nE) {
  __shared__ int lh[256];
  __shared__ int lbase[256];
  __shared__ int srow[EPB1 + 2];
  const int t = threadIdx.x;
  const int e0 = blockIdx.x * EPB1;
  const int e1 = min(e0 + EPB1, nE);
  const int cnt = e1 - e0;
  for (int i = t; i < 256; i += 512) lh[i] = 0;
  __syncthreads();
  for (int i = t; i < cnt; i += 512) {
    const int r = erow[e0 + i];
    srow[i] = r;
    atomicAdd(&lh[r >> 9], 1);
  }
  __syncthreads();
  for (int i = t; i < NBUCK2; i += 512) {
    const int c = lh[i];
    lbase[i] = c ? atomicAdd(&bcur[i * 16], c) : 0;
  }
  __syncthreads();
  for (int i = t; i < 256; i += 512) lh[i] = 0;
  __syncthreads();
  for (int i = t; i < cnt; i += 512) {
    const int r = srow[i];
    const int b = r >> 9;
    const int pos = lbase[b] + atomicAdd(&lh[b], 1);
    const unsigned short bw = f2bf(ew[e0 + i]);            // w in [0,1) -> sign 0, fits 15 bits
    const unsigned rec = ((unsigned)ecol[e0 + i] << 15) | (unsigned)bw;
    tmp[pos] = make_uint2(rec, (unsigned)r);
  }
}

// ---- part2: per-bucket counting sort into final CSR order (L2-local 33 KB window) -----------
__global__ __launch_bounds__(512) void part2_kernel(
    const int* __restrict__ row_start, const uint2* __restrict__ tmp,
    unsigned* __restrict__ spack, int N, int nE) {
  __shared__ int cur[512];
  const int b = blockIdx.x;
  const int r0 = b << 9;
  const int t = threadIdx.x;
  const int r = r0 + t;
  cur[t] = (r < N) ? row_start[r] : nE;
  __syncthreads();
  const int w0 = row_start[r0];
  const int w1 = (r0 + 512 < N) ? row_start[r0 + 512] : nE;
  for (int i = w0 + t; i < w1; i += 512) {
    const uint2 rc = tmp[i];
    const int pos = atomicAdd(&cur[(int)rc.y - r0], 1);
    spack[pos] = rc.x;
  }
}

// ---------------- CSR SpMM (bf16 gather, packed 4B edge records) -----------------------------
__global__ __launch_bounds__(256) void spmm_csr128_bf16(
    const unsigned short* __restrict__ feat, const int* __restrict__ row_start,
    const unsigned* __restrict__ spack, float* __restrict__ out, int M) {
  const int wid = (blockIdx.x * 256 + threadIdx.x) >> 6;
  const int lane = threadIdx.x & 63;
  if (wid >= M) return;
  const int s = row_start[wid], e = row_start[wid + 1];
  float2 acc = make_float2(0.f, 0.f);
  int j = s;
  for (; j + 1 < e; j += 2) {
    const unsigned rec0 = spack[j];
    const unsigned rec1 = spack[j + 1];
    const float w0 = bf2f((unsigned short)(rec0 & 0x7fff));
    const float w1 = bf2f((unsigned short)(rec1 & 0x7fff));
    const ushort2 v0 = *(const ushort2*)(feat + (size_t)(rec0 >> 15) * 128 + lane * 2);
    const ushort2 v1 = *(const ushort2*)(feat + (size_t)(rec1 >> 15) * 128 + lane * 2);
    acc.x = fmaf(bf2f(v0.x), w0, acc.x);
    acc.y = fmaf(bf2f(v0.y), w0, acc.y);
    acc.x = fmaf(bf2f(v1.x), w1, acc.x);
    acc.y = fmaf(bf2f(v1.y), w1, acc.y);
  }
  if (j < e) {
    const unsigned rec0 = spack[j];
    const float w0 = bf2f((unsigned short)(rec0 & 0x7fff));
    const ushort2 v0 = *(const ushort2*)(feat + (size_t)(rec0 >> 15) * 128 + lane * 2);
    acc.x = fmaf(bf2f(v0.x), w0, acc.x);
    acc.y = fmaf(bf2f(v0.y), w0, acc.y);
  }
  *(float2*)(out + (size_t)wid * 128 + lane * 2) = acc;
}

__global__ __launch_bounds__(256) void spmm_csr64_bf16(
    const unsigned short* __restrict__ feat, const int* __restrict__ row_start,
    const unsigned* __restrict__ spack, float* __restrict__ out, int M) {
  const int wid = (blockIdx.x * 256 + threadIdx.x) >> 5;
  const int lane = threadIdx.x & 31;
  if (wid >= M) return;
  const int s = row_start[wid], e = row_start[wid + 1];
  float2 acc = make_float2(0.f, 0.f);
  int j = s;
  for (; j + 1 < e; j += 2) {
    const unsigned rec0 = spack[j];
    const unsigned rec1 = spack[j + 1];
    const float w0 = bf2f((unsigned short)(rec0 & 0x7fff));
    const float w1 = bf2f((unsigned short)(rec1 & 0x7fff));
    const ushort2 v0 = *(const ushort2*)(feat + (size_t)(rec0 >> 15) * 64 + lane * 2);
    const ushort2 v1 = *(const ushort2*)(feat + (size_t)(rec1 >> 15) * 64 + lane * 2);
    acc.x = fmaf(bf2f(v0.x), w0, acc.x);
    acc.y = fmaf(bf2f(v0.y), w0, acc.y);
    acc.x = fmaf(bf2f(v1.x), w1, acc.x);
    acc.y = fmaf(bf2f(v1.y), w1, acc.y);
  }
  if (j < e) {
    const unsigned rec0 = spack[j];
    const float w0 = bf2f((unsigned short)(rec0 & 0x7fff));
    const ushort2 v0 = *(const ushort2*)(feat + (size_t)(rec0 >> 15) * 64 + lane * 2);
    acc.x = fmaf(bf2f(v0.x), w0, acc.x);
    acc.y = fmaf(bf2f(v0.y), w0, acc.y);
  }
  *(float2*)(out + (size_t)wid * 64 + lane * 2) = acc;
}

// ---------------- head ----------------------------------------------------------------------
__global__ __launch_bounds__(256) void final_kernel(
    const float* __restrict__ s2, const float* __restrict__ pred_w,
    const float* __restrict__ pred_b, const float* __restrict__ b2,
    float* __restrict__ out, int M) {
  __shared__ float pw[512];
  __shared__ float pb[8];
  __shared__ float bb[64];
  const int tid = threadIdx.x;
  for (int i = tid; i < 512; i += 256) pw[i] = pred_w[i];
  if (tid < 8) pb[tid] = pred_b[tid];
  if (tid < 64) bb[tid] = b2[tid];
  __syncthreads();
  const int node = blockIdx.x * 32 + (tid >> 3);
  const int c = tid & 7;
  if (node >= M) return;
  const float* row = s2 + (size_t)node * 64;
  float acc = pb[c];
  #pragma unroll 8
  for (int k = 0; k < 64; ++k)
    acc = fmaf(fmaxf(row[k] + bb[k], 0.f), pw[c * 64 + k], acc);
  out[node * 8 + c] = acc;
}

// ---------------- zero fill ------------------------------------------------------------------
__global__ void zero_kernel(float4* __restrict__ p, int n4) {
  int i = blockIdx.x * blockDim.x + threadIdx.x;
  const int stride = gridDim.x * blockDim.x;
  for (; i < n4; i += stride) p[i] = make_float4(0.f, 0.f, 0.f, 0.f);
}

extern "C" void kernel_launch(void* const* d_in, const int* in_sizes, int n_in,
                              void* d_out, int out_size, void* d_ws, size_t ws_size,
                              hipStream_t stream) {
  const float* feat0  = (const float*)d_in[0];
  const float* feat1  = (const float*)d_in[1];
  const float* fc0_w  = (const float*)d_in[2];
  const float* fc0_b  = (const float*)d_in[3];
  const float* fc1_w  = (const float*)d_in[4];
  const float* fc1_b  = (const float*)d_in[5];
  const float* W1     = (const float*)d_in[6];
  const float* b1     = (const float*)d_in[7];
  const float* W2     = (const float*)d_in[8];
  const float* b2     = (const float*)d_in[9];
  const float* pred_w = (const float*)d_in[10];
  const float* pred_b = (const float*)d_in[11];
  const int*   erow   = (const int*)d_in[12];
  const int*   ecol   = (const int*)d_in[13];
  const float* ew     = (const float*)d_in[14];
  float* out = (float*)d_out;
  const int nE = in_sizes[12];
  const int N = N_NODES;

  char* ws = (char*)d_ws;
  size_t off = 0;
  unsigned short* M0T = (unsigned short*)(ws + off); off += 32768;
  unsigned short* M1T = (unsigned short*)(ws + off); off += 65536;
  unsigned short* W2T = (unsigned short*)(ws + off); off += 16384;
  float* cb = (float*)(ws + off); off += 1024;
  int* counts    = (int*)(ws + off); off += 400000;
  int* excl      = (int*)(ws + off); off += 400000;
  int* row_start = (int*)(ws + off); off += 400016;
  int* bsum      = (int*)(ws + off); off += 512;
  int* boff      = (int*)(ws + off); off += 2544;             // pad
  int* bcur      = (int*)(ws + off); off += NBUCK2 * 64;      // padded cursors (1/line)
  uint2* tmp     = (uint2*)(ws + off); off += (size_t)nE * 8; // 12.8 MB
  unsigned* spack = (unsigned*)(ws + off); off += (size_t)nE * 4;  // 6.4 MB
  unsigned short* h = (unsigned short*)(ws + off); off += (size_t)N * 128 * 2;  // 25.6 MB
  float* s = (float*)(ws + off); off += (size_t)N * 128 * 4;  // 51.2 MB

  const int nb1 = (N + SCAN_E - 1) / SCAN_E;  // 98

  // ---- CSR build (counting sort, two-level) ----
  hipLaunchKernelGGL(zero_kernel, dim3(128), dim3(256), 0, stream,
                     (float4*)counts, 400000 / 16);
  hipLaunchKernelGGL(hist_kernel, dim3((nE + 255) / 256), dim3(256), 0, stream,
                     erow, counts, nE);
  hipLaunchKernelGGL(scan1_kernel, dim3(nb1), dim3(256), 0, stream,
                     counts, excl, bsum, N);
  hipLaunchKernelGGL(scan2_kernel, dim3(1), dim3(256), 0, stream, bsum, boff, nb1);
  hipLaunchKernelGGL(scan3_kernel, dim3((N + 256) / 256), dim3(256), 0, stream,
                     excl, boff, row_start, bcur, N, nE);
  hipLaunchKernelGGL(part1_kernel, dim3(NB1), dim3(512), 0, stream,
                     erow, ecol, ew, bcur, tmp, nE);
  hipLaunchKernelGGL(part2_kernel, dim3(NBUCK2), dim3(512), 0, stream,
                     row_start, tmp, spack, N, nE);

  // ---- dense pipeline ----
  hipLaunchKernelGGL(prep_small_kernel, dim3(225), dim3(256), 0, stream,
                     fc0_w, fc1_w, fc0_b, fc1_b, W1, W2, M0T, M1T, W2T, cb);
  hipLaunchKernelGGL((mfma_gemm_kernel<128, 128, false, true>), dim3((N_TYPE + 63) / 64),
                     dim3(256), 0, stream, feat0, M0T, nullptr, cb, (void*)h, N_TYPE);
  hipLaunchKernelGGL((mfma_gemm_kernel<128, 256, false, true>), dim3((N_TYPE + 63) / 64),
                     dim3(256), 0, stream, feat1, M1T, nullptr, cb + 128,
                     (void*)(h + (size_t)N_TYPE * 128), N_TYPE);
  // s1 = adj @ h1  (fp32)
  hipLaunchKernelGGL(spmm_csr128_bf16, dim3((N * 64 + 255) / 256), dim3(256), 0, stream,
                     h, row_start, spack, s, N);
  // h2 = bf16(relu(s1 + b1) @ W2)
  hipLaunchKernelGGL((mfma_gemm_kernel<64, 128, true, true>), dim3((N + 63) / 64),
                     dim3(256), 0, stream, s, W2T, b1, nullptr, (void*)h, N);
  // s2 = adj @ h2  (fp32)
  hipLaunchKernelGGL(spmm_csr64_bf16, dim3((N * 32 + 255) / 256), dim3(256), 0, stream,
                     h, row_start, spack, s, N);
  // head
  hipLaunchKernelGGL(final_kernel, dim3((N + 31) / 32), dim3(256), 0, stream,
                     s, pred_w, pred_b, b2, out, N);
}